// Round 1
// baseline (3668.215 us; speedup 1.0000x reference)
//
#include <hip/hip_runtime.h>
#include <cstdint>
#include <cstddef>

// Problem dims (fixed by setup_inputs)
#define BB    2048   // batch
#define SS    256    // state dim
#define HH    256    // hidden dim
#define AA    2      // action dim
#define TT    50     // timesteps
#define NB    8      // batch rows per block
#define NBLK  256    // blocks (= BB/NB) == #CUs
#define NTHR  256    // threads per block

struct Params {
  const float* x;
  const float* fu[3]; const float* fv[3]; const float* fs[3];
  const float* f4u; const float* f4v; const float* f4s;
  const float* W[3]; const float* bs[3];
  const float* W4; const float* b4;
  float* out;
  float* wt;          // [3][256*256]  W transposed: wt[l][k*256+h] = W[l][h][k]
  float* partials;    // [2 slots][4 layers][6 stats][NBLK]
  unsigned* bar;      // [ctr, gen]
  float* xT;          // [TT][BB*SS]  (optional)
  int use_xt;
};

__device__ __forceinline__ void pstore(float* p, float v) {
  __hip_atomic_store(p, v, __ATOMIC_RELAXED, __HIP_MEMORY_SCOPE_AGENT);
}
__device__ __forceinline__ float pload(const float* p) {
  return __hip_atomic_load(p, __ATOMIC_RELAXED, __HIP_MEMORY_SCOPE_AGENT);
}

// Sense-reversing grid barrier. All 256 blocks are co-resident
// (grid == #CUs, launch_bounds caps VGPRs for >=2 blocks/CU).
__device__ __forceinline__ void gridbar(unsigned* bar) {
  __syncthreads();
  if (threadIdx.x == 0) {
    unsigned* ctr = bar;
    unsigned* gen = bar + 1;
    unsigned g = __hip_atomic_load(gen, __ATOMIC_RELAXED, __HIP_MEMORY_SCOPE_AGENT);
    unsigned old = __hip_atomic_fetch_add(ctr, 1u, __ATOMIC_ACQ_REL, __HIP_MEMORY_SCOPE_AGENT);
    if (old == (unsigned)(NBLK - 1)) {
      __hip_atomic_store(ctr, 0u, __ATOMIC_RELAXED, __HIP_MEMORY_SCOPE_AGENT);
      __hip_atomic_store(gen, g + 1u, __ATOMIC_RELEASE, __HIP_MEMORY_SCOPE_AGENT);
    } else {
      while (__hip_atomic_load(gen, __ATOMIC_ACQUIRE, __HIP_MEMORY_SCOPE_AGENT) == g) {
        __builtin_amdgcn_s_sleep(2);
      }
    }
  }
  __syncthreads();
}

__global__ __launch_bounds__(NTHR, 2)
void snn_kernel(Params p) {
#pragma clang fp contract(off)
  const int tid  = threadIdx.x;
  const int blk  = blockIdx.x;
  const int gtid = blk * NTHR + tid;

  __shared__ __align__(16) float in_lds[HH * NB];   // [k][j]  (input / spikes)
  __shared__ float wred[4][6];
  __shared__ float scal[4][2];                      // per-layer V_m, V_theta
  __shared__ float l4u[16], l4v[16], l4s[16], l4t[16], l4acc[16], l4vn[16], l4vth[16];

  // ---------------- prologue ----------------
  {
    // transpose W (coalesced writes)
    int h = gtid & 255, k = gtid >> 8;
    #pragma unroll
    for (int l = 0; l < 3; ++l)
      p.wt[l * 65536 + k * 256 + h] = p.W[l][h * 256 + k];
  }
  if (p.use_xt) {
    // xT[t][b*256+s] = x[(b*256+s)*50 + t]; 8 strips of 50 per thread.
    for (int q = 0; q < 8; ++q) {
      int sid = gtid + q * 65536;
      const float* src = p.x + (size_t)sid * TT;
      for (int t = 0; t < TT; ++t)
        p.xT[(size_t)t * (BB * SS) + sid] = src[t];
    }
  }

  // per-thread cell mapping: 2 h's x 4 b's
  const int h0    = tid & 127;
  const int jbase = (tid >> 7) * 4;

  float u[3][2][4], v[3][2][4], s[3][2][4], tp[3][2][4];
  #pragma unroll
  for (int l = 0; l < 3; ++l)
    #pragma unroll
    for (int hh = 0; hh < 2; ++hh)
      #pragma unroll
      for (int jj = 0; jj < 4; ++jj) {
        size_t idx = (size_t)(blk * NB + jbase + jj) * HH + h0 + 128 * hh;
        u[l][hh][jj]  = p.fu[l][idx];
        v[l][hh][jj]  = p.fv[l][idx];
        s[l][hh][jj]  = p.fs[l][idx];
        tp[l][hh][jj] = 0.5f;
      }
  if (tid < 16) {
    int j = tid >> 1, a = tid & 1;
    size_t idx = (size_t)(blk * NB + j) * AA + a;
    l4u[tid] = p.f4u[idx]; l4v[tid] = p.f4v[idx]; l4s[tid] = p.f4s[idx];
    l4t[tid] = 0.5f; l4acc[tid] = 0.0f;
  }

  gridbar(p.bar);   // wt / xT ready everywhere; also covers LDS init

  auto load_xt = [&](int t) {
    if (p.use_xt) {
      const float* base = p.xT + (size_t)t * (BB * SS) + (size_t)blk * NB * SS;
      #pragma unroll
      for (int j = 0; j < NB; ++j)
        in_lds[tid * NB + j] = base[j * SS + tid];
    } else {
      #pragma unroll
      for (int j = 0; j < NB; ++j)
        in_lds[tid * NB + j] = p.x[((size_t)(blk * NB + j) * SS + tid) * TT + t];
    }
  };

  load_xt(0);

  #pragma unroll 1
  for (int t = 0; t < TT; ++t) {
    __syncthreads();   // in_lds (xt) ready

    // ---------------- layers 1..3 ----------------
    #pragma unroll
    for (int l = 0; l < 3; ++l) {
      const float* WtL = p.wt + l * 65536;
      float acc[2][4];
      #pragma unroll
      for (int hh = 0; hh < 2; ++hh)
        #pragma unroll
        for (int jj = 0; jj < 4; ++jj) acc[hh][jj] = 0.0f;

      #pragma unroll 4
      for (int k = 0; k < HH; ++k) {
        float w0 = WtL[k * 256 + h0];
        float w1 = WtL[k * 256 + h0 + 128];
        float4 iv = *reinterpret_cast<const float4*>(&in_lds[k * NB + jbase]);
        acc[0][0] = fmaf(iv.x, w0, acc[0][0]);
        acc[0][1] = fmaf(iv.y, w0, acc[0][1]);
        acc[0][2] = fmaf(iv.z, w0, acc[0][2]);
        acc[0][3] = fmaf(iv.w, w0, acc[0][3]);
        acc[1][0] = fmaf(iv.x, w1, acc[1][0]);
        acc[1][1] = fmaf(iv.y, w1, acc[1][1]);
        acc[1][2] = fmaf(iv.z, w1, acc[1][2]);
        acc[1][3] = fmaf(iv.w, w1, acc[1][3]);
      }

      const float bb0 = p.bs[l][h0];
      const float bb1 = p.bs[l][h0 + 128];
      float sv = 0.f, svt = 0.f;
      float mxv = -3.402823466e38f, mnv = 3.402823466e38f;
      float mxvt = -3.402823466e38f, mnvt = 3.402823466e38f;
      float sn[2][4];
      #pragma unroll
      for (int hh = 0; hh < 2; ++hh) {
        const float bbx = hh ? bb1 : bb0;
        #pragma unroll
        for (int jj = 0; jj < 4; ++jj) {
          float un = fmaf(u[l][hh][jj], 0.5f, acc[hh][jj]) + bbx; // (0.5u exact)+mm, +b
          float vp = v[l][hh][jj];
          float vd = (vp * 0.75f) * (1.0f - s[l][hh][jj]);
          float vn = vd + un;
          float en = expf((vp - vn) / 3.0f) - 1.0f;
          float vt = 0.5f * tp[l][hh][jj] + 0.5f * en;
          float sx = (vn > vt) ? 1.0f : 0.0f;
          u[l][hh][jj] = un; v[l][hh][jj] = vn; s[l][hh][jj] = sx;
          sn[hh][jj] = sx;
          sv += vn; svt += vt;
          mxv = fmaxf(mxv, vn); mnv = fminf(mnv, vn);
          mxvt = fmaxf(mxvt, vt); mnvt = fminf(mnvt, vt);
        }
      }
      // wave butterfly (fixed tree -> deterministic)
      #pragma unroll
      for (int m = 1; m < 64; m <<= 1) {
        sv  += __shfl_xor(sv, m);   svt += __shfl_xor(svt, m);
        mxv  = fmaxf(mxv,  __shfl_xor(mxv, m));  mnv  = fminf(mnv,  __shfl_xor(mnv, m));
        mxvt = fmaxf(mxvt, __shfl_xor(mxvt, m)); mnvt = fminf(mnvt, __shfl_xor(mnvt, m));
      }
      __syncthreads();   // all GEMM reads of in_lds done
      if ((tid & 63) == 0) {
        int wv = tid >> 6;
        wred[wv][0] = sv;  wred[wv][1] = mxv;  wred[wv][2] = mnv;
        wred[wv][3] = svt; wred[wv][4] = mxvt; wred[wv][5] = mnvt;
      }
      // publish spikes as next layer's input
      *reinterpret_cast<float4*>(&in_lds[h0 * NB + jbase]) =
          make_float4(sn[0][0], sn[0][1], sn[0][2], sn[0][3]);
      *reinterpret_cast<float4*>(&in_lds[(h0 + 128) * NB + jbase]) =
          make_float4(sn[1][0], sn[1][1], sn[1][2], sn[1][3]);
      __syncthreads();
      if (tid < 6) {
        int st = tid; float r;
        if (st == 0 || st == 3)
          r = ((wred[0][st] + wred[1][st]) + wred[2][st]) + wred[3][st];
        else if (st == 1 || st == 4)
          r = fmaxf(fmaxf(wred[0][st], wred[1][st]), fmaxf(wred[2][st], wred[3][st]));
        else
          r = fminf(fminf(wred[0][st], wred[1][st]), fminf(wred[2][st], wred[3][st]));
        pstore(&p.partials[(((size_t)(t & 1) * 4 + l) * 6 + st) * NBLK + blk], r);
      }
    }

    // ---------------- layer 4 (H -> 2) ----------------
    {
      const int g = tid >> 4, c = tid & 15;
      const int j4 = g >> 1, a4 = g & 1;
      float part = 0.0f;
      #pragma unroll
      for (int i = 0; i < 16; ++i) {
        int k = c + 16 * i;
        part = fmaf(in_lds[k * NB + j4], p.W4[a4 * HH + k], part);
      }
      #pragma unroll
      for (int m = 1; m < 16; m <<= 1) part += __shfl_xor(part, m);
      if (c == 0) {
        float un = fmaf(l4u[g], 0.5f, part) + p.b4[a4];
        float vp = l4v[g];
        float vd = (vp * 0.75f) * (1.0f - l4s[g]);
        float vn = vd + un;
        float en = expf((vp - vn) / 3.0f) - 1.0f;
        float vt = 0.5f * l4t[g] + 0.5f * en;
        float sx = (vn > vt) ? 1.0f : 0.0f;
        l4u[g] = un; l4v[g] = vn; l4s[g] = sx;
        l4acc[g] += sx; l4vn[g] = vn; l4vth[g] = vt;
      }
    }
    __syncthreads();
    if (tid == 0) {
      float sv4 = l4vn[0], mx4 = l4vn[0], mn4 = l4vn[0];
      float st4 = l4vth[0], mxt4 = l4vth[0], mnt4 = l4vth[0];
      for (int g2 = 1; g2 < 16; ++g2) {
        sv4 += l4vn[g2]; mx4 = fmaxf(mx4, l4vn[g2]); mn4 = fminf(mn4, l4vn[g2]);
        st4 += l4vth[g2]; mxt4 = fmaxf(mxt4, l4vth[g2]); mnt4 = fminf(mnt4, l4vth[g2]);
      }
      float* pp = p.partials + ((size_t)(t & 1) * 4 + 3) * 6 * NBLK + blk;
      pstore(pp + 0 * NBLK, sv4);  pstore(pp + 1 * NBLK, mx4);  pstore(pp + 2 * NBLK, mn4);
      pstore(pp + 3 * NBLK, st4);  pstore(pp + 4 * NBLK, mxt4); pstore(pp + 5 * NBLK, mnt4);
    }

    if (t < TT - 1) {
      gridbar(p.bar);

      // every block redundantly combines the 256 partials (identical fixed tree)
      {
        const int wv = tid >> 6, ln = tid & 63;
        const float* pb = p.partials + ((size_t)(t & 1) * 4 + wv) * 6 * NBLK;
        float r[6];
        #pragma unroll
        for (int st = 0; st < 6; ++st) {
          const float* q = pb + st * NBLK;
          float a0 = pload(q + ln), a1 = pload(q + ln + 64);
          float a2 = pload(q + ln + 128), a3 = pload(q + ln + 192);
          float rr;
          if (st == 0 || st == 3) {
            rr = ((a0 + a1) + a2) + a3;
            #pragma unroll
            for (int m = 1; m < 64; m <<= 1) rr += __shfl_xor(rr, m);
          } else if (st == 1 || st == 4) {
            rr = fmaxf(fmaxf(a0, a1), fmaxf(a2, a3));
            #pragma unroll
            for (int m = 1; m < 64; m <<= 1) rr = fmaxf(rr, __shfl_xor(rr, m));
          } else {
            rr = fminf(fminf(a0, a1), fminf(a2, a3));
            #pragma unroll
            for (int m = 1; m < 64; m <<= 1) rr = fminf(rr, __shfl_xor(rr, m));
          }
          r[st] = rr;
        }
        if (ln == 0) {
          const float invN = (wv == 3) ? (1.0f / 4096.0f) : (1.0f / 524288.0f); // exact pow2
          float rv = r[1] - r[2];
          float Vm = (r[0] * invN) - 0.2f * rv;
          float rt = r[4] - r[5];
          float Vt = (r[3] * invN) - 0.2f * rt;
          scal[wv][0] = Vm; scal[wv][1] = Vt;
        }
      }
      __syncthreads();

      // temporal updates (need only own registers + scalars)
      #pragma unroll
      for (int l = 0; l < 3; ++l) {
        const float Vm = scal[l][0], Vt = scal[l][1];
        #pragma unroll
        for (int hh = 0; hh < 2; ++hh)
          #pragma unroll
          for (int jj = 0; jj < 4; ++jj) {
            float d = v[l][hh][jj] - Vm;
            float sp = logf(1.0f + expf(d * 0.25f));
            tp[l][hh][jj] = (0.01f * d + Vt) + sp;
          }
      }
      if (tid < 16) {
        const float Vm = scal[3][0], Vt = scal[3][1];
        float d = l4v[tid] - Vm;
        float sp = logf(1.0f + expf(d * 0.25f));
        l4t[tid] = (0.01f * d + Vt) + sp;
      }
      load_xt(t + 1);
    }
  }

  __syncthreads();
  if (tid < 16) {
    int j = tid >> 1, a = tid & 1;
    p.out[(size_t)(blk * NB + j) * AA + a] = l4acc[tid] / 50.0f;
  }
}

extern "C" void kernel_launch(void* const* d_in, const int* in_sizes, int n_in,
                              void* d_out, int out_size, void* d_ws, size_t ws_size,
                              hipStream_t stream) {
  Params p;
  p.x     = (const float*)d_in[0];
  p.fu[0] = (const float*)d_in[1];  p.fv[0] = (const float*)d_in[2];  p.fs[0] = (const float*)d_in[3];
  p.fu[1] = (const float*)d_in[4];  p.fv[1] = (const float*)d_in[5];  p.fs[1] = (const float*)d_in[6];
  p.fu[2] = (const float*)d_in[7];  p.fv[2] = (const float*)d_in[8];  p.fs[2] = (const float*)d_in[9];
  p.f4u   = (const float*)d_in[10]; p.f4v   = (const float*)d_in[11]; p.f4s   = (const float*)d_in[12];
  p.W[0]  = (const float*)d_in[13]; p.bs[0] = (const float*)d_in[14];
  p.W[1]  = (const float*)d_in[15]; p.bs[1] = (const float*)d_in[16];
  p.W[2]  = (const float*)d_in[17]; p.bs[2] = (const float*)d_in[18];
  p.W4    = (const float*)d_in[19]; p.b4    = (const float*)d_in[20];
  p.out   = (float*)d_out;

  float* ws   = (float*)d_ws;
  p.wt        = ws;                       // 3*65536 floats
  p.partials  = ws + 196608;              // 12288 floats
  p.bar       = (unsigned*)(ws + 208896); // 2 uints
  p.xT        = ws + 208960;              // 50*524288 floats (optional)
  size_t need = ((size_t)208960 + (size_t)TT * BB * SS) * sizeof(float);
  p.use_xt    = (ws_size >= need) ? 1 : 0;

  hipMemsetAsync((void*)p.bar, 0, 2 * sizeof(unsigned), stream);
  snn_kernel<<<dim3(NBLK), dim3(NTHR), 0, stream>>>(p);
}

// Round 2
// 3431.695 us; speedup vs baseline: 1.0689x; 1.0689x over previous
//
#include <hip/hip_runtime.h>
#include <cstdint>
#include <cstddef>

// Problem dims (fixed by setup_inputs)
#define BB    2048   // batch
#define SS    256    // state dim
#define HH    256    // hidden dim
#define AA    2      // action dim
#define TT    50     // timesteps
#define NB    4      // batch rows per block
#define NBLK  512    // blocks (= BB/NB) -> 2 blocks/CU
#define NTHR  256    // threads per block

struct Params {
  const float* x;
  const float* fu[3]; const float* fv[3]; const float* fs[3];
  const float* f4u; const float* f4v; const float* f4s;
  const float* W[3]; const float* bs[3];
  const float* W4; const float* b4;
  float* out;
  float* partials;    // [2 slots][4 layers][6 stats][NBLK]
  unsigned* bar;      // [ctr, gen] (monotone)
  float* xT;          // [TT][BB*SS]  (optional)
  int use_xt;
};

__device__ __forceinline__ void pstore(float* p, float v) {
  __hip_atomic_store(p, v, __ATOMIC_RELAXED, __HIP_MEMORY_SCOPE_AGENT);
}
__device__ __forceinline__ float pload(const float* p) {
  return __hip_atomic_load(p, __ATOMIC_RELAXED, __HIP_MEMORY_SCOPE_AGENT);
}

// Split grid barrier (monotone generation; bar[0]=ctr, bar[1]=gen).
// All NBLK blocks are co-resident: 512 blocks, 2/CU, guaranteed by
// __launch_bounds__(256,2) (VGPR<=256) + tiny LDS.
__device__ __forceinline__ void bar_arrive(unsigned* bar, int b) {
  __syncthreads();  // all threads' prior LDS+global ops drained
  if (threadIdx.x == 0) {
    unsigned old = __hip_atomic_fetch_add(bar, 1u, __ATOMIC_ACQ_REL, __HIP_MEMORY_SCOPE_AGENT);
    if (old == (unsigned)((b + 1) * NBLK - 1))
      __hip_atomic_store(bar + 1, (unsigned)(b + 1), __ATOMIC_RELEASE, __HIP_MEMORY_SCOPE_AGENT);
  }
}
__device__ __forceinline__ void bar_wait(unsigned* bar, int b) {
  if (threadIdx.x == 0) {
    while ((int)__hip_atomic_load(bar + 1, __ATOMIC_ACQUIRE, __HIP_MEMORY_SCOPE_AGENT) < b + 1)
      __builtin_amdgcn_s_sleep(2);
  }
  __syncthreads();
}

__global__ __launch_bounds__(NTHR, 2)
void snn_kernel(Params p) {
#pragma clang fp contract(off)
  const int tid  = threadIdx.x;
  const int blk  = blockIdx.x;
  const int gtid = blk * NTHR + tid;

  __shared__ __align__(16) float in_lds[HH * NB];   // [k][j] (input / spikes)
  __shared__ float wred[4][6];
  __shared__ float scal[4][2];                      // per-layer V_m, V_theta
  __shared__ float l4u[8], l4v[8], l4s[8], l4t[8], l4acc[8], l4vn[8], l4vth[8];

  // ---------------- prologue: transpose x -> xT[t][b*SS+s] ----------------
  if (p.use_xt) {
    for (int q = 0; q < 4; ++q) {
      int sid = gtid + q * (NBLK * NTHR);
      const float* src = p.x + (size_t)sid * TT;
      for (int t = 0; t < TT; ++t)
        p.xT[(size_t)t * (BB * SS) + sid] = src[t];
    }
  }

  // per-thread cells: 1 h x NB batch rows
  const int h0 = tid;  // 0..255

  float u[3][NB], v[3][NB], s[3][NB], tp[3][NB];
  #pragma unroll
  for (int l = 0; l < 3; ++l)
    #pragma unroll
    for (int j = 0; j < NB; ++j) {
      size_t idx = (size_t)(blk * NB + j) * HH + h0;
      u[l][j]  = p.fu[l][idx];
      v[l][j]  = p.fv[l][idx];
      s[l][j]  = p.fs[l][idx];
      tp[l][j] = 0.5f;
    }
  if (tid < 2 * NB) {
    int j = tid >> 1, a = tid & 1;
    size_t idx = (size_t)(blk * NB + j) * AA + a;
    l4u[tid] = p.f4u[idx]; l4v[tid] = p.f4v[idx]; l4s[tid] = p.f4s[idx];
    l4t[tid] = 0.5f; l4acc[tid] = 0.0f;
  }

  const float bL[3] = { p.bs[0][h0], p.bs[1][h0], p.bs[2][h0] };
  const float* Wrow[3] = { p.W[0] + (size_t)h0 * SS,
                           p.W[1] + (size_t)h0 * HH,
                           p.W[2] + (size_t)h0 * HH };

  // init barrier: xT visible everywhere (also covers l4 LDS init before use)
  bar_arrive(p.bar, 0);
  bar_wait(p.bar, 0);

  auto load_xt = [&](int t) {
    if (p.use_xt) {
      const float* base = p.xT + (size_t)t * (BB * SS) + (size_t)blk * NB * SS;
      #pragma unroll
      for (int j = 0; j < NB; ++j)
        in_lds[tid * NB + j] = base[j * SS + tid];
    } else {
      #pragma unroll
      for (int j = 0; j < NB; ++j)
        in_lds[tid * NB + j] = p.x[((size_t)(blk * NB + j) * SS + tid) * TT + t];
    }
  };

  // GEMM: acc[j] += sum_k W[h0][k] * in[k][j], k ascending (bit-exact chain)
  auto gemm = [&](const float* __restrict__ wrow, float acc[NB]) {
    acc[0] = acc[1] = acc[2] = acc[3] = 0.0f;
    #pragma unroll 4
    for (int k = 0; k < HH; k += 4) {
      float4 w  = *reinterpret_cast<const float4*>(wrow + k);
      float4 i0 = *reinterpret_cast<const float4*>(&in_lds[(k + 0) * NB]);
      float4 i1 = *reinterpret_cast<const float4*>(&in_lds[(k + 1) * NB]);
      float4 i2 = *reinterpret_cast<const float4*>(&in_lds[(k + 2) * NB]);
      float4 i3 = *reinterpret_cast<const float4*>(&in_lds[(k + 3) * NB]);
      acc[0] = fmaf(i0.x, w.x, acc[0]); acc[1] = fmaf(i0.y, w.x, acc[1]);
      acc[2] = fmaf(i0.z, w.x, acc[2]); acc[3] = fmaf(i0.w, w.x, acc[3]);
      acc[0] = fmaf(i1.x, w.y, acc[0]); acc[1] = fmaf(i1.y, w.y, acc[1]);
      acc[2] = fmaf(i1.z, w.y, acc[2]); acc[3] = fmaf(i1.w, w.y, acc[3]);
      acc[0] = fmaf(i2.x, w.z, acc[0]); acc[1] = fmaf(i2.y, w.z, acc[1]);
      acc[2] = fmaf(i2.z, w.z, acc[2]); acc[3] = fmaf(i2.w, w.z, acc[3]);
      acc[0] = fmaf(i3.x, w.w, acc[0]); acc[1] = fmaf(i3.y, w.w, acc[1]);
      acc[2] = fmaf(i3.z, w.w, acc[2]); acc[3] = fmaf(i3.w, w.w, acc[3]);
    }
  };

  load_xt(0);

  #pragma unroll 1
  for (int t = 0; t < TT; ++t) {
    __syncthreads();   // in_lds (x_t) ready

    // ---------------- layers 1..3 ----------------
    #pragma unroll
    for (int l = 0; l < 3; ++l) {
      float acc[NB];
      gemm(Wrow[l], acc);

      if (l == 0 && t > 0) {
        // stats barrier for step t-1 — hidden behind the layer-1 GEMM above
        bar_wait(p.bar, t);
        {
          const int wv = tid >> 6, ln = tid & 63;
          const float* pb = p.partials + ((size_t)((t - 1) & 1) * 4 + wv) * 6 * NBLK;
          float r[6];
          #pragma unroll
          for (int st = 0; st < 6; ++st) {
            const float* q = pb + st * NBLK;
            float a0 = pload(q + ln),        a1 = pload(q + ln + 64);
            float a2 = pload(q + ln + 128),  a3 = pload(q + ln + 192);
            float a4 = pload(q + ln + 256),  a5 = pload(q + ln + 320);
            float a6 = pload(q + ln + 384),  a7 = pload(q + ln + 448);
            float rr;
            if (st == 0 || st == 3) {
              rr = ((((((a0 + a1) + a2) + a3) + a4) + a5) + a6) + a7;
              #pragma unroll
              for (int m = 1; m < 64; m <<= 1) rr += __shfl_xor(rr, m);
            } else if (st == 1 || st == 4) {
              rr = fmaxf(fmaxf(fmaxf(a0, a1), fmaxf(a2, a3)),
                         fmaxf(fmaxf(a4, a5), fmaxf(a6, a7)));
              #pragma unroll
              for (int m = 1; m < 64; m <<= 1) rr = fmaxf(rr, __shfl_xor(rr, m));
            } else {
              rr = fminf(fminf(fminf(a0, a1), fminf(a2, a3)),
                         fminf(fminf(a4, a5), fminf(a6, a7)));
              #pragma unroll
              for (int m = 1; m < 64; m <<= 1) rr = fminf(rr, __shfl_xor(rr, m));
            }
            r[st] = rr;
          }
          if (ln == 0) {
            const float invN = (wv == 3) ? (1.0f / 4096.0f) : (1.0f / 524288.0f);
            scal[wv][0] = (r[0] * invN) - 0.2f * (r[1] - r[2]);
            scal[wv][1] = (r[3] * invN) - 0.2f * (r[4] - r[5]);
          }
        }
        __syncthreads();
        // temporal updates for all layers from v(t-1) (still in regs / l4v)
        #pragma unroll
        for (int l2 = 0; l2 < 3; ++l2) {
          const float Vm = scal[l2][0], Vt = scal[l2][1];
          #pragma unroll
          for (int j = 0; j < NB; ++j) {
            float d  = v[l2][j] - Vm;
            float sp = logf(1.0f + expf(d * 0.25f));
            tp[l2][j] = (0.01f * d + Vt) + sp;
          }
        }
        if (tid < 2 * NB) {
          const float Vm = scal[3][0], Vt = scal[3][1];
          float d  = l4v[tid] - Vm;
          float sp = logf(1.0f + expf(d * 0.25f));
          l4t[tid] = (0.01f * d + Vt) + sp;
        }
        __syncthreads();  // l4t visible before layer-4 phase
      }

      // ---- LIF update + stats for layer l ----
      const float bbx = bL[l];
      float sv = 0.f, svt = 0.f;
      float mxv = -3.402823466e38f, mnv = 3.402823466e38f;
      float mxvt = -3.402823466e38f, mnvt = 3.402823466e38f;
      float sn[NB];
      #pragma unroll
      for (int j = 0; j < NB; ++j) {
        float un = fmaf(u[l][j], 0.5f, acc[j]) + bbx;
        float vp = v[l][j];
        float vd = (vp * 0.75f) * (1.0f - s[l][j]);
        float vn = vd + un;
        float en = expf((vp - vn) / 3.0f) - 1.0f;
        float vt = 0.5f * tp[l][j] + 0.5f * en;
        float sx = (vn > vt) ? 1.0f : 0.0f;
        u[l][j] = un; v[l][j] = vn; s[l][j] = sx;
        sn[j] = sx;
        sv += vn; svt += vt;
        mxv = fmaxf(mxv, vn); mnv = fminf(mnv, vn);
        mxvt = fmaxf(mxvt, vt); mnvt = fminf(mnvt, vt);
      }
      #pragma unroll
      for (int m = 1; m < 64; m <<= 1) {
        sv  += __shfl_xor(sv, m);   svt += __shfl_xor(svt, m);
        mxv  = fmaxf(mxv,  __shfl_xor(mxv, m));  mnv  = fminf(mnv,  __shfl_xor(mnv, m));
        mxvt = fmaxf(mxvt, __shfl_xor(mxvt, m)); mnvt = fminf(mnvt, __shfl_xor(mnvt, m));
      }
      __syncthreads();   // all GEMM reads of in_lds done; wred slot free
      if ((tid & 63) == 0) {
        int wv = tid >> 6;
        wred[wv][0] = sv;  wred[wv][1] = mxv;  wred[wv][2] = mnv;
        wred[wv][3] = svt; wred[wv][4] = mxvt; wred[wv][5] = mnvt;
      }
      // publish spikes as next layer's input
      *reinterpret_cast<float4*>(&in_lds[h0 * NB]) =
          make_float4(sn[0], sn[1], sn[2], sn[3]);
      __syncthreads();
      if (tid < 6) {
        int st = tid; float r;
        if (st == 0 || st == 3)
          r = ((wred[0][st] + wred[1][st]) + wred[2][st]) + wred[3][st];
        else if (st == 1 || st == 4)
          r = fmaxf(fmaxf(wred[0][st], wred[1][st]), fmaxf(wred[2][st], wred[3][st]));
        else
          r = fminf(fminf(wred[0][st], wred[1][st]), fminf(wred[2][st], wred[3][st]));
        pstore(&p.partials[(((size_t)(t & 1) * 4 + l) * 6 + st) * NBLK + blk], r);
      }
      __syncthreads();   // spikes + wred consumption complete
    }

    // ---------------- layer 4 (H -> 2) ----------------
    {
      const int g = tid >> 4, c = tid & 15;
      if (g < 2 * NB) {
        const int j4 = g >> 1, a4 = g & 1;
        float part = 0.0f;
        #pragma unroll
        for (int i = 0; i < 16; ++i) {
          int k = c + 16 * i;
          part = fmaf(in_lds[k * NB + j4], p.W4[a4 * HH + k], part);
        }
        #pragma unroll
        for (int m = 1; m < 16; m <<= 1) part += __shfl_xor(part, m);
        if (c == 0) {
          float un = fmaf(l4u[g], 0.5f, part) + p.b4[a4];
          float vp = l4v[g];
          float vd = (vp * 0.75f) * (1.0f - l4s[g]);
          float vn = vd + un;
          float en = expf((vp - vn) / 3.0f) - 1.0f;
          float vt = 0.5f * l4t[g] + 0.5f * en;
          float sx = (vn > vt) ? 1.0f : 0.0f;
          l4u[g] = un; l4v[g] = vn; l4s[g] = sx;
          l4acc[g] += sx; l4vn[g] = vn; l4vth[g] = vt;
        }
      }
    }
    __syncthreads();   // layer-4 reads of in_lds done; l4vn/l4vth visible

    if (t < TT - 1) load_xt(t + 1);   // writes in_lds (safe after sync)

    if (tid == 0) {
      float sv4 = l4vn[0], mx4 = l4vn[0], mn4 = l4vn[0];
      float st4 = l4vth[0], mxt4 = l4vth[0], mnt4 = l4vth[0];
      #pragma unroll
      for (int g2 = 1; g2 < 2 * NB; ++g2) {
        sv4 += l4vn[g2]; mx4 = fmaxf(mx4, l4vn[g2]); mn4 = fminf(mn4, l4vn[g2]);
        st4 += l4vth[g2]; mxt4 = fmaxf(mxt4, l4vth[g2]); mnt4 = fminf(mnt4, l4vth[g2]);
      }
      float* pp = p.partials + ((size_t)(t & 1) * 4 + 3) * 6 * NBLK + blk;
      pstore(pp + 0 * NBLK, sv4);  pstore(pp + 1 * NBLK, mx4);  pstore(pp + 2 * NBLK, mn4);
      pstore(pp + 3 * NBLK, st4);  pstore(pp + 4 * NBLK, mxt4); pstore(pp + 5 * NBLK, mnt4);
    }

    if (t < TT - 1) bar_arrive(p.bar, t + 1);  // includes __syncthreads
  }

  __syncthreads();
  if (tid < 2 * NB) {
    int j = tid >> 1, a = tid & 1;
    p.out[(size_t)(blk * NB + j) * AA + a] = l4acc[tid] / 50.0f;
  }
}

extern "C" void kernel_launch(void* const* d_in, const int* in_sizes, int n_in,
                              void* d_out, int out_size, void* d_ws, size_t ws_size,
                              hipStream_t stream) {
  Params p;
  p.x     = (const float*)d_in[0];
  p.fu[0] = (const float*)d_in[1];  p.fv[0] = (const float*)d_in[2];  p.fs[0] = (const float*)d_in[3];
  p.fu[1] = (const float*)d_in[4];  p.fv[1] = (const float*)d_in[5];  p.fs[1] = (const float*)d_in[6];
  p.fu[2] = (const float*)d_in[7];  p.fv[2] = (const float*)d_in[8];  p.fs[2] = (const float*)d_in[9];
  p.f4u   = (const float*)d_in[10]; p.f4v   = (const float*)d_in[11]; p.f4s   = (const float*)d_in[12];
  p.W[0]  = (const float*)d_in[13]; p.bs[0] = (const float*)d_in[14];
  p.W[1]  = (const float*)d_in[15]; p.bs[1] = (const float*)d_in[16];
  p.W[2]  = (const float*)d_in[17]; p.bs[2] = (const float*)d_in[18];
  p.W4    = (const float*)d_in[19]; p.b4    = (const float*)d_in[20];
  p.out   = (float*)d_out;

  float* ws   = (float*)d_ws;
  p.partials  = ws;                        // 2*4*6*512 = 24576 floats
  p.bar       = (unsigned*)(ws + 24576);   // 2 uints (pad to 64)
  p.xT        = ws + 24640;                // 50*524288 floats (optional)
  size_t need = ((size_t)24640 + (size_t)TT * BB * SS) * sizeof(float);
  p.use_xt    = (ws_size >= need) ? 1 : 0;

  hipMemsetAsync((void*)p.bar, 0, 2 * sizeof(unsigned), stream);
  snn_kernel<<<dim3(NBLK), dim3(NTHR), 0, stream>>>(p);
}